// Round 1
// baseline (768.138 us; speedup 1.0000x reference)
//
#include <hip/hip_runtime.h>
#include <math.h>

#define XP 960
typedef __attribute__((ext_vector_type(8))) short short8;
typedef __attribute__((ext_vector_type(4))) float f32x4;
typedef __attribute__((ext_vector_type(4))) float float4v;

// Packed bf16 weights in MFMA B-fragment order, module-global (no ws dependency).
// Offsets (in shorts):
//  w1s  : 0       (8 kt * 28 nt * 64 * 8 = 114688)
//  w1v1 : 114688  (4*8*64*8  = 16384)
//  w1v2 : 131072  (2*4*64*8  = 4096)
//  w2s  : 135168  (8*16*64*8 = 65536)
//  w2v1 : 200704  (16384)
//  w2v2 : 217088  (4096)   total 221184 shorts
__device__ short g_pack[221184];

__device__ __forceinline__ short f2bf(float f) {
    union { float f; unsigned u; } v; v.f = f;
    unsigned r = (v.u + 0x7fffu + ((v.u >> 16) & 1u)) >> 16;
    return (short)r;
}
__device__ __forceinline__ float bf2f(short s) {
    union { float f; unsigned u; } v;
    v.u = ((unsigned)(unsigned short)s) << 16;
    return v.f;
}
__device__ __forceinline__ float ssp(float v, float c) {
    float sp = fmaxf(v, 0.f) + log1pf(expf(-fabsf(v)));
    return c * (sp - 0.69314718055994531f);
}

__global__ void pack_weights(const float* __restrict__ w1s, const float* __restrict__ w1v1,
                             const float* __restrict__ w1v2, const float* __restrict__ w2s,
                             const float* __restrict__ w2v1, const float* __restrict__ w2v2) {
    int g = blockIdx.x * blockDim.x + threadIdx.x;
    const float* src; int NT, N, dstoff, lg;
    if      (g < 14336) { src = w1s;  NT = 28; N = 448; dstoff = 0;      lg = g; }
    else if (g < 16384) { src = w1v1; NT = 8;  N = 128; dstoff = 114688; lg = g - 14336; }
    else if (g < 16896) { src = w1v2; NT = 4;  N = 64;  dstoff = 131072; lg = g - 16384; }
    else if (g < 25088) { src = w2s;  NT = 16; N = 256; dstoff = 135168; lg = g - 16896; }
    else if (g < 27136) { src = w2v1; NT = 8;  N = 128; dstoff = 200704; lg = g - 25088; }
    else if (g < 27648) { src = w2v2; NT = 4;  N = 64;  dstoff = 217088; lg = g - 27136; }
    else return;
    int lane = lg & 63;
    int t = lg >> 6;
    int nt = t % NT;
    int kt = t / NT;
    int k0 = kt * 32 + (lane >> 4) * 8;
    int n  = nt * 16 + (lane & 15);
    short* dst = g_pack + dstoff + (size_t)lg * 8;
#pragma unroll
    for (int j = 0; j < 8; j++) dst[j] = f2bf(src[(size_t)(k0 + j) * N + n]);
}

#define MFMA(a, b, c) __builtin_amdgcn_mfma_f32_16x16x32_bf16((a), (b), (c), 0, 0, 0)

__global__ __launch_bounds__(256, 4) void fused_kernel(const float* __restrict__ x,
                                                       float* __restrict__ out,
                                                       float c_ssp) {
    // Per-wave staging buffers (all cross-layout traffic is intra-wave).
    __shared__ __align__(16) short sstage[4][16 * 264];  // scalars [16][256] pitch 264; reused as v-stage
    __shared__ __align__(16) short gstage[4][16 * 200];  // gates   [16][192] pitch 200

    const int lane = threadIdx.x & 63;
    const int wave = threadIdx.x >> 6;
    const int q = lane >> 4, l15 = lane & 15;
    const int row0 = blockIdx.x * 64 + wave * 16;

    short* ss = sstage[wave];
    short* gs = gstage[wave];

    const short8* pw1s  = (const short8*)(g_pack + 0);
    const short8* pw1v1 = (const short8*)(g_pack + 114688);
    const short8* pw1v2 = (const short8*)(g_pack + 131072);
    const short8* pw2s  = (const short8*)(g_pack + 135168);
    const short8* pw2v1 = (const short8*)(g_pack + 200704);
    const short8* pw2v2 = (const short8*)(g_pack + 217088);

    const float* xa = x + (size_t)(row0 + l15) * XP;  // A-fragment row for this lane
    const float* xr = x + (size_t)row0 * XP;          // epilogue rows row0 + q*4 + r
    float* yr = out + (size_t)row0 * XP;

    const float s1  = 0.0625f;                // 1/sqrt(256)
    const float sv1 = 0.08838834764831845f;   // 1/sqrt(128)
    const float sv2 = 0.125f;                 // 1/sqrt(64)

    // ---- Load x0 A-fragments (K=256 -> 8 k-tiles) ----
    short8 a0[8];
#pragma unroll
    for (int kt = 0; kt < 8; kt++) {
        const float* p = xa + kt * 32 + q * 8;
        float4v u0 = *(const float4v*)p;
        float4v u1 = *(const float4v*)(p + 4);
        short8 f;
        f[0] = f2bf(u0[0]); f[1] = f2bf(u0[1]); f[2] = f2bf(u0[2]); f[3] = f2bf(u0[3]);
        f[4] = f2bf(u1[0]); f[5] = f2bf(u1[1]); f[6] = f2bf(u1[2]); f[7] = f2bf(u1[3]);
        a0[kt] = f;
    }

    // ---- GEMM1a: s = x0 @ w1s * s1, ssp, stage scalars+gates ----
#pragma unroll 1
    for (int np = 0; np < 14; np++) {
        f32x4 acc0 = {0.f, 0.f, 0.f, 0.f}, acc1 = {0.f, 0.f, 0.f, 0.f};
#pragma unroll
        for (int kt = 0; kt < 8; kt++) {
            short8 b0 = pw1s[(kt * 28 + 2 * np + 0) * 64 + lane];
            short8 b1 = pw1s[(kt * 28 + 2 * np + 1) * 64 + lane];
            acc0 = MFMA(a0[kt], b0, acc0);
            acc1 = MFMA(a0[kt], b1, acc1);
        }
#pragma unroll
        for (int half = 0; half < 2; half++) {
            f32x4 a = half ? acc1 : acc0;
            int col = (2 * np + half) * 16 + l15;
#pragma unroll
            for (int r = 0; r < 4; r++) {
                short bv = f2bf(ssp(a[r] * s1, c_ssp));
                if (col < 256) ss[(q * 4 + r) * 264 + col] = bv;
                else           gs[(q * 4 + r) * 200 + (col - 256)] = bv;
            }
        }
    }
    __syncthreads();

    // ---- GEMM2a: y0 = scalars @ w2s * s1 + x0 ----
    {
        short8 as[8];
#pragma unroll
        for (int kt = 0; kt < 8; kt++)
            as[kt] = *(const short8*)&ss[l15 * 264 + kt * 32 + q * 8];
#pragma unroll 1
        for (int np = 0; np < 8; np++) {
            f32x4 acc0 = {0.f, 0.f, 0.f, 0.f}, acc1 = {0.f, 0.f, 0.f, 0.f};
#pragma unroll
            for (int kt = 0; kt < 8; kt++) {
                short8 b0 = pw2s[(kt * 16 + 2 * np + 0) * 64 + lane];
                short8 b1 = pw2s[(kt * 16 + 2 * np + 1) * 64 + lane];
                acc0 = MFMA(as[kt], b0, acc0);
                acc1 = MFMA(as[kt], b1, acc1);
            }
#pragma unroll
            for (int half = 0; half < 2; half++) {
                f32x4 a = half ? acc1 : acc0;
                int col = (2 * np + half) * 16 + l15;
#pragma unroll
                for (int r = 0; r < 4; r++) {
                    size_t off = (size_t)(q * 4 + r) * XP + col;
                    yr[off] = xr[off] + a[r] * s1;
                }
            }
        }
    }

    // ---- v1: 3 channels of 128x128 GEMMs with gating ----
#pragma unroll 1
    for (int c = 0; c < 3; c++) {
        short8 a1[4];
#pragma unroll
        for (int kt = 0; kt < 4; kt++) {
            short8 f;
#pragma unroll
            for (int j = 0; j < 8; j++) {
                int i = kt * 32 + q * 8 + j;
                f[j] = f2bf(xa[256 + i * 3 + c]);
            }
            a1[kt] = f;
        }
        __syncthreads();  // previous readers of ss (v-stage) are done
#pragma unroll 1
        for (int np = 0; np < 4; np++) {
            f32x4 acc0 = {0.f, 0.f, 0.f, 0.f}, acc1 = {0.f, 0.f, 0.f, 0.f};
#pragma unroll
            for (int kt = 0; kt < 4; kt++) {
                short8 b0 = pw1v1[(kt * 8 + 2 * np + 0) * 64 + lane];
                short8 b1 = pw1v1[(kt * 8 + 2 * np + 1) * 64 + lane];
                acc0 = MFMA(a1[kt], b0, acc0);
                acc1 = MFMA(a1[kt], b1, acc1);
            }
#pragma unroll
            for (int half = 0; half < 2; half++) {
                f32x4 a = half ? acc1 : acc0;
                int o = (2 * np + half) * 16 + l15;
#pragma unroll
                for (int r = 0; r < 4; r++) {
                    float g = bf2f(gs[(q * 4 + r) * 200 + o]);
                    ss[(q * 4 + r) * 136 + o] = f2bf(a[r] * sv1 * g);
                }
            }
        }
        __syncthreads();
        short8 av[4];
#pragma unroll
        for (int kt = 0; kt < 4; kt++)
            av[kt] = *(const short8*)&ss[l15 * 136 + kt * 32 + q * 8];
#pragma unroll 1
        for (int np = 0; np < 4; np++) {
            f32x4 acc0 = {0.f, 0.f, 0.f, 0.f}, acc1 = {0.f, 0.f, 0.f, 0.f};
#pragma unroll
            for (int kt = 0; kt < 4; kt++) {
                short8 b0 = pw2v1[(kt * 8 + 2 * np + 0) * 64 + lane];
                short8 b1 = pw2v1[(kt * 8 + 2 * np + 1) * 64 + lane];
                acc0 = MFMA(av[kt], b0, acc0);
                acc1 = MFMA(av[kt], b1, acc1);
            }
#pragma unroll
            for (int half = 0; half < 2; half++) {
                f32x4 a = half ? acc1 : acc0;
                int o = (2 * np + half) * 16 + l15;
#pragma unroll
                for (int r = 0; r < 4; r++) {
                    size_t off = (size_t)(q * 4 + r) * XP + 256 + o * 3 + c;
                    yr[off] = xr[off] + a[r] * sv1;
                }
            }
        }
    }

    // ---- v2: 5 channels of 64x64 GEMMs with gating ----
#pragma unroll 1
    for (int c = 0; c < 5; c++) {
        short8 a2[2];
#pragma unroll
        for (int kt = 0; kt < 2; kt++) {
            short8 f;
#pragma unroll
            for (int j = 0; j < 8; j++) {
                int i = kt * 32 + q * 8 + j;
                f[j] = f2bf(xa[640 + i * 5 + c]);
            }
            a2[kt] = f;
        }
        __syncthreads();
#pragma unroll 1
        for (int np = 0; np < 2; np++) {
            f32x4 acc0 = {0.f, 0.f, 0.f, 0.f}, acc1 = {0.f, 0.f, 0.f, 0.f};
#pragma unroll
            for (int kt = 0; kt < 2; kt++) {
                short8 b0 = pw1v2[(kt * 4 + 2 * np + 0) * 64 + lane];
                short8 b1 = pw1v2[(kt * 4 + 2 * np + 1) * 64 + lane];
                acc0 = MFMA(a2[kt], b0, acc0);
                acc1 = MFMA(a2[kt], b1, acc1);
            }
#pragma unroll
            for (int half = 0; half < 2; half++) {
                f32x4 a = half ? acc1 : acc0;
                int o = (2 * np + half) * 16 + l15;
#pragma unroll
                for (int r = 0; r < 4; r++) {
                    float g = bf2f(gs[(q * 4 + r) * 200 + 128 + o]);
                    ss[(q * 4 + r) * 72 + o] = f2bf(a[r] * sv2 * g);
                }
            }
        }
        __syncthreads();
        short8 av[2];
#pragma unroll
        for (int kt = 0; kt < 2; kt++)
            av[kt] = *(const short8*)&ss[l15 * 72 + kt * 32 + q * 8];
#pragma unroll 1
        for (int np = 0; np < 2; np++) {
            f32x4 acc0 = {0.f, 0.f, 0.f, 0.f}, acc1 = {0.f, 0.f, 0.f, 0.f};
#pragma unroll
            for (int kt = 0; kt < 2; kt++) {
                short8 b0 = pw2v2[(kt * 4 + 2 * np + 0) * 64 + lane];
                short8 b1 = pw2v2[(kt * 4 + 2 * np + 1) * 64 + lane];
                acc0 = MFMA(av[kt], b0, acc0);
                acc1 = MFMA(av[kt], b1, acc1);
            }
#pragma unroll
            for (int half = 0; half < 2; half++) {
                f32x4 a = half ? acc1 : acc0;
                int o = (2 * np + half) * 16 + l15;
#pragma unroll
                for (int r = 0; r < 4; r++) {
                    size_t off = (size_t)(q * 4 + r) * XP + 640 + o * 5 + c;
                    yr[off] = xr[off] + a[r] * sv2;
                }
            }
        }
    }
}

static float compute_cssp() {
    const int N = 200001;
    const double dz = 20.0 / 200000.0;
    double sum = 0.0;
    for (int i = 0; i < N; i++) {
        double z = -10.0 + dz * i;
        double f = (z > 0 ? z : 0.0) + log1p(exp(-fabs(z))) - 0.69314718055994530942;
        double phi = exp(-0.5 * z * z) * 0.39894228040143267794;  // 1/sqrt(2*pi)
        double y = f * f * phi;
        sum += (i == 0 || i == N - 1) ? 0.5 * y : y;
    }
    return (float)(1.0 / sqrt(sum * dz));
}

extern "C" void kernel_launch(void* const* d_in, const int* in_sizes, int n_in,
                              void* d_out, int out_size, void* d_ws, size_t ws_size,
                              hipStream_t stream) {
    const float* x    = (const float*)d_in[0];
    const float* w1s  = (const float*)d_in[1];
    const float* w1v1 = (const float*)d_in[2];
    const float* w1v2 = (const float*)d_in[3];
    const float* w2s  = (const float*)d_in[4];
    const float* w2v1 = (const float*)d_in[5];
    const float* w2v2 = (const float*)d_in[6];
    float* out = (float*)d_out;

    static const float c_ssp = compute_cssp();  // pure deterministic constant

    int rows = in_sizes[0] / XP;
    int blocks = rows / 64;

    pack_weights<<<108, 256, 0, stream>>>(w1s, w1v1, w1v2, w2s, w2v1, w2v2);
    fused_kernel<<<blocks, 256, 0, stream>>>(x, out, c_ssp);
}

// Round 2
// 625.781 us; speedup vs baseline: 1.2275x; 1.2275x over previous
//
#include <hip/hip_runtime.h>
#include <math.h>

#define XP 960
typedef __attribute__((ext_vector_type(8))) short short8;
typedef __attribute__((ext_vector_type(4))) float f32x4;
typedef __attribute__((ext_vector_type(4))) float fv4;
typedef __attribute__((ext_vector_type(4))) unsigned uint4v;

// Packed bf16 weights in MFMA fragment order (serves as B-frag for X@W and
// identically as A-frag for W^T@X^T). Offsets in shorts:
//  w1s:0  w1v1:114688  w1v2:131072  w2s:135168  w2v1:200704  w2v2:217088
__device__ short g_pack[221184];

__device__ __forceinline__ short f2bf(float f) {
    union { float f; unsigned u; } v; v.f = f;
    unsigned r = (v.u + 0x7fffu + ((v.u >> 16) & 1u)) >> 16;
    return (short)r;
}
// pack two floats -> dword of 2 bf16 (round-to-nearest, half-up)
__device__ __forceinline__ unsigned pk2(float a, float b) {
    union { float f; unsigned u; } x, y; x.f = a; y.f = b;
    return ((x.u + 0x8000u) >> 16) | ((y.u + 0x8000u) & 0xffff0000u);
}
__device__ __forceinline__ short8 mk8(unsigned d0, unsigned d1, unsigned d2, unsigned d3) {
    union { uint4v u; short8 s; } cv;
    cv.u = (uint4v){d0, d1, d2, d3};
    return cv.s;
}
__device__ __forceinline__ float ssp(float v, float c) {
    // c * (softplus(v) - ln2), stable: max(v,0) + ln2*log2(1 + 2^(-|v|*log2e))
    float t = exp2f(fabsf(v) * -1.44269504088896340736f);
    float sp = fmaxf(v, 0.f) + 0.69314718055994530942f * __log2f(1.0f + t);
    return c * (sp - 0.69314718055994530942f);
}

#define WSYNC() asm volatile("s_waitcnt lgkmcnt(0)" ::: "memory")
#define MFMA(a, b, c) __builtin_amdgcn_mfma_f32_16x16x32_bf16((a), (b), (c), 0, 0, 0)
#define NTL(p) __builtin_nontemporal_load((const fv4*)(p))
#define NTS(p, v) __builtin_nontemporal_store((v), (fv4*)(p))

__global__ void pack_weights(const float* __restrict__ w1s, const float* __restrict__ w1v1,
                             const float* __restrict__ w1v2, const float* __restrict__ w2s,
                             const float* __restrict__ w2v1, const float* __restrict__ w2v2) {
    int g = blockIdx.x * blockDim.x + threadIdx.x;
    const float* src; int NT, N, dstoff, lg;
    if      (g < 14336) { src = w1s;  NT = 28; N = 448; dstoff = 0;      lg = g; }
    else if (g < 16384) { src = w1v1; NT = 8;  N = 128; dstoff = 114688; lg = g - 14336; }
    else if (g < 16896) { src = w1v2; NT = 4;  N = 64;  dstoff = 131072; lg = g - 16384; }
    else if (g < 25088) { src = w2s;  NT = 16; N = 256; dstoff = 135168; lg = g - 16896; }
    else if (g < 27136) { src = w2v1; NT = 8;  N = 128; dstoff = 200704; lg = g - 25088; }
    else if (g < 27648) { src = w2v2; NT = 4;  N = 64;  dstoff = 217088; lg = g - 27136; }
    else return;
    int lane = lg & 63;
    int t = lg >> 6;
    int nt = t % NT;
    int kt = t / NT;
    int k0 = kt * 32 + (lane >> 4) * 8;
    int n  = nt * 16 + (lane & 15);
    short* dst = g_pack + dstoff + (size_t)lg * 8;
#pragma unroll
    for (int j = 0; j < 8; j++) dst[j] = f2bf(src[(size_t)(k0 + j) * N + n]);
}

__global__ __launch_bounds__(256, 3) void fused_kernel(const float* __restrict__ x,
                                                       float* __restrict__ out,
                                                       float c_ssp) {
    // One per-wave arena: scalars [16 samp][256k], later v1 [16][3*136], v2 [16][5*72].
    // Sample pitch 408 shorts (816B, 16B-aligned); all k-offsets 16B-aligned for b128.
    __shared__ __align__(16) short arena[4][16 * 408];

    const int lane = threadIdx.x & 63;
    const int wave = threadIdx.x >> 6;
    const int q = lane >> 4, l15 = lane & 15;
    const int row0 = blockIdx.x * 64 + wave * 16;
    short* S = arena[wave];
    unsigned* Sd = (unsigned*)S;
    const int dwb = l15 * 204 + q * 2;   // dword base for C-layout pair-stores
    const short* Sr = S + l15 * 408 + q * 8;  // b128 read base (k = kt*32+q*8)

    const short8* pw1s  = (const short8*)(g_pack + 0);
    const short8* pw1v1 = (const short8*)(g_pack + 114688);
    const short8* pw1v2 = (const short8*)(g_pack + 131072);
    const short8* pw2s  = (const short8*)(g_pack + 135168);
    const short8* pw2v1 = (const short8*)(g_pack + 200704);
    const short8* pw2v2 = (const short8*)(g_pack + 217088);

    const float* xrow = x + (size_t)(row0 + l15) * XP;
    float* yrow = out + (size_t)(row0 + l15) * XP;

    const float S1  = 0.0625f;                // 1/sqrt(256)
    const float SV1 = 0.08838834764831845f;   // 1/sqrt(128)
    const float SV2 = 0.125f;                 // 1/sqrt(64)

    // ---- phase 0: x0 fragments (lane = own sample row; serves as B operand) ----
    short8 xf0[8];
#pragma unroll
    for (int kt = 0; kt < 8; kt++) {
        fv4 u0 = *(const fv4*)(xrow + kt * 32 + q * 8);
        fv4 u1 = *(const fv4*)(xrow + kt * 32 + q * 8 + 4);
        xf0[kt] = mk8(pk2(u0[0], u0[1]), pk2(u0[2], u0[3]), pk2(u1[0], u1[1]), pk2(u1[2], u1[3]));
    }

    // ---- phase 1: S^T = W1s^T X0^T ; scalars -> LDS (B-layout), gates -> regs ----
#pragma unroll 1
    for (int tp = 0; tp < 8; tp++) {          // scalar tiles t = 0..15
        f32x4 a0 = {0.f,0.f,0.f,0.f}, a1 = {0.f,0.f,0.f,0.f};
#pragma unroll
        for (int kt = 0; kt < 8; kt++) {
            a0 = MFMA(pw1s[(kt * 28 + 2 * tp + 0) * 64 + lane], xf0[kt], a0);
            a1 = MFMA(pw1s[(kt * 28 + 2 * tp + 1) * 64 + lane], xf0[kt], a1);
        }
#pragma unroll
        for (int h = 0; h < 2; h++) {
            f32x4 a = h ? a1 : a0;
            int t = 2 * tp + h;
            Sd[dwb + t * 8]     = pk2(ssp(a[0] * S1, c_ssp), ssp(a[1] * S1, c_ssp));
            Sd[dwb + t * 8 + 1] = pk2(ssp(a[2] * S1, c_ssp), ssp(a[3] * S1, c_ssp));
        }
    }
    f32x4 gacc[12];
#pragma unroll
    for (int tp = 0; tp < 6; tp++) {          // gate tiles t = 16..27 (static gacc idx)
        f32x4 a0 = {0.f,0.f,0.f,0.f}, a1 = {0.f,0.f,0.f,0.f};
#pragma unroll
        for (int kt = 0; kt < 8; kt++) {
            a0 = MFMA(pw1s[(kt * 28 + 16 + 2 * tp + 0) * 64 + lane], xf0[kt], a0);
            a1 = MFMA(pw1s[(kt * 28 + 16 + 2 * tp + 1) * 64 + lane], xf0[kt], a1);
        }
        gacc[2 * tp]     = (f32x4){ssp(a0[0]*S1,c_ssp), ssp(a0[1]*S1,c_ssp), ssp(a0[2]*S1,c_ssp), ssp(a0[3]*S1,c_ssp)};
        gacc[2 * tp + 1] = (f32x4){ssp(a1[0]*S1,c_ssp), ssp(a1[1]*S1,c_ssp), ssp(a1[2]*S1,c_ssp), ssp(a1[3]*S1,c_ssp)};
    }
    WSYNC();

    // ---- phase 2: Y0^T = W2s^T Scal^T ; epilogue = per-lane float4 on own row ----
    short8 sf[8];
#pragma unroll
    for (int kt = 0; kt < 8; kt++) sf[kt] = *(const short8*)(Sr + kt * 32);
#pragma unroll 1
    for (int tp = 0; tp < 8; tp++) {
        f32x4 a0 = {0.f,0.f,0.f,0.f}, a1 = {0.f,0.f,0.f,0.f};
#pragma unroll
        for (int kt = 0; kt < 8; kt++) {
            a0 = MFMA(pw2s[(kt * 16 + 2 * tp + 0) * 64 + lane], sf[kt], a0);
            a1 = MFMA(pw2s[(kt * 16 + 2 * tp + 1) * 64 + lane], sf[kt], a1);
        }
#pragma unroll
        for (int h = 0; h < 2; h++) {
            f32x4 a = h ? a1 : a0;
            int col = (2 * tp + h) * 16 + q * 4;
            fv4 r = NTL(xrow + col);
            fv4 o = {r[0] + a[0] * S1, r[1] + a[1] * S1, r[2] + a[2] * S1, r[3] + a[3] * S1};
            NTS(yrow + col, o);
        }
    }

    // ---- phase 3: v1 (3 interleaved channels, 128x128) ----
    short8 xf1[3][4];
#pragma unroll
    for (int kt = 0; kt < 4; kt++) {
        float b[24];
        const float* p = xrow + 256 + 3 * (kt * 32 + q * 8);
#pragma unroll
        for (int i = 0; i < 6; i++) *(fv4*)(b + 4 * i) = *(const fv4*)(p + 4 * i);
#pragma unroll
        for (int c = 0; c < 3; c++)
            xf1[c][kt] = mk8(pk2(b[c], b[c+3]), pk2(b[c+6], b[c+9]),
                             pk2(b[c+12], b[c+15]), pk2(b[c+18], b[c+21]));
    }
#pragma unroll
    for (int c = 0; c < 3; c++) {
#pragma unroll
        for (int tp = 0; tp < 4; tp++) {
            f32x4 a0 = {0.f,0.f,0.f,0.f}, a1 = {0.f,0.f,0.f,0.f};
#pragma unroll
            for (int kt = 0; kt < 4; kt++) {
                a0 = MFMA(pw1v1[(kt * 8 + 2 * tp + 0) * 64 + lane], xf1[c][kt], a0);
                a1 = MFMA(pw1v1[(kt * 8 + 2 * tp + 1) * 64 + lane], xf1[c][kt], a1);
            }
#pragma unroll
            for (int h = 0; h < 2; h++) {
                f32x4 a = h ? a1 : a0;
                int t = 2 * tp + h;
                f32x4 g = gacc[t];
                Sd[dwb + c * 68 + t * 8]     = pk2(a[0]*SV1*g[0], a[1]*SV1*g[1]);
                Sd[dwb + c * 68 + t * 8 + 1] = pk2(a[2]*SV1*g[2], a[3]*SV1*g[3]);
            }
        }
    }
    WSYNC();
    short8 vf[3][4];
#pragma unroll
    for (int c = 0; c < 3; c++)
#pragma unroll
        for (int kt = 0; kt < 4; kt++)
            vf[c][kt] = *(const short8*)(Sr + c * 136 + kt * 32);
#pragma unroll 1
    for (int t = 0; t < 8; t++) {
        f32x4 ac0 = {0.f,0.f,0.f,0.f}, ac1 = {0.f,0.f,0.f,0.f}, ac2 = {0.f,0.f,0.f,0.f};
#pragma unroll
        for (int kt = 0; kt < 4; kt++) {
            short8 w = pw2v1[(kt * 8 + t) * 64 + lane];
            ac0 = MFMA(w, vf[0][kt], ac0);
            ac1 = MFMA(w, vf[1][kt], ac1);
            ac2 = MFMA(w, vf[2][kt], ac2);
        }
        int base = 256 + 3 * (t * 16 + q * 4);
        fv4 r0 = NTL(xrow + base), r1 = NTL(xrow + base + 4), r2 = NTL(xrow + base + 8);
        fv4 o0 = {r0[0]+ac0[0]*SV1, r0[1]+ac1[0]*SV1, r0[2]+ac2[0]*SV1, r0[3]+ac0[1]*SV1};
        fv4 o1 = {r1[0]+ac1[1]*SV1, r1[1]+ac2[1]*SV1, r1[2]+ac0[2]*SV1, r1[3]+ac1[2]*SV1};
        fv4 o2 = {r2[0]+ac2[2]*SV1, r2[1]+ac0[3]*SV1, r2[2]+ac1[3]*SV1, r2[3]+ac2[3]*SV1};
        NTS(yrow + base, o0); NTS(yrow + base + 4, o1); NTS(yrow + base + 8, o2);
    }

    // ---- phase 4: v2 (5 interleaved channels, 64x64) ----
    short8 xf2[5][2];
#pragma unroll
    for (int kt = 0; kt < 2; kt++) {
        float b[40];
        const float* p = xrow + 640 + 5 * (kt * 32 + q * 8);
#pragma unroll
        for (int i = 0; i < 10; i++) *(fv4*)(b + 4 * i) = *(const fv4*)(p + 4 * i);
#pragma unroll
        for (int c = 0; c < 5; c++)
            xf2[c][kt] = mk8(pk2(b[c], b[c+5]), pk2(b[c+10], b[c+15]),
                             pk2(b[c+20], b[c+25]), pk2(b[c+30], b[c+35]));
    }
#pragma unroll
    for (int c = 0; c < 5; c++) {
#pragma unroll
        for (int tp = 0; tp < 2; tp++) {
            f32x4 a0 = {0.f,0.f,0.f,0.f}, a1 = {0.f,0.f,0.f,0.f};
#pragma unroll
            for (int kt = 0; kt < 2; kt++) {
                a0 = MFMA(pw1v2[(kt * 4 + 2 * tp + 0) * 64 + lane], xf2[c][kt], a0);
                a1 = MFMA(pw1v2[(kt * 4 + 2 * tp + 1) * 64 + lane], xf2[c][kt], a1);
            }
#pragma unroll
            for (int h = 0; h < 2; h++) {
                f32x4 a = h ? a1 : a0;
                int t = 2 * tp + h;
                f32x4 g = gacc[8 + t];
                Sd[dwb + c * 36 + t * 8]     = pk2(a[0]*SV2*g[0], a[1]*SV2*g[1]);
                Sd[dwb + c * 36 + t * 8 + 1] = pk2(a[2]*SV2*g[2], a[3]*SV2*g[3]);
            }
        }
    }
    WSYNC();
    short8 vf2[5][2];
#pragma unroll
    for (int c = 0; c < 5; c++)
#pragma unroll
        for (int kt = 0; kt < 2; kt++)
            vf2[c][kt] = *(const short8*)(Sr + c * 72 + kt * 32);
#pragma unroll 1
    for (int t = 0; t < 4; t++) {
        f32x4 b0 = {0.f,0.f,0.f,0.f}, b1 = {0.f,0.f,0.f,0.f}, b2 = {0.f,0.f,0.f,0.f},
              b3 = {0.f,0.f,0.f,0.f}, b4 = {0.f,0.f,0.f,0.f};
#pragma unroll
        for (int kt = 0; kt < 2; kt++) {
            short8 w = pw2v2[(kt * 4 + t) * 64 + lane];
            b0 = MFMA(w, vf2[0][kt], b0);
            b1 = MFMA(w, vf2[1][kt], b1);
            b2 = MFMA(w, vf2[2][kt], b2);
            b3 = MFMA(w, vf2[3][kt], b3);
            b4 = MFMA(w, vf2[4][kt], b4);
        }
        int base = 640 + 5 * (t * 16 + q * 4);
        fv4 r0 = NTL(xrow + base),      r1 = NTL(xrow + base + 4),
            r2 = NTL(xrow + base + 8),  r3 = NTL(xrow + base + 12),
            r4 = NTL(xrow + base + 16);
        fv4 o0 = {r0[0]+b0[0]*SV2, r0[1]+b1[0]*SV2, r0[2]+b2[0]*SV2, r0[3]+b3[0]*SV2};
        fv4 o1 = {r1[0]+b4[0]*SV2, r1[1]+b0[1]*SV2, r1[2]+b1[1]*SV2, r1[3]+b2[1]*SV2};
        fv4 o2 = {r2[0]+b3[1]*SV2, r2[1]+b4[1]*SV2, r2[2]+b0[2]*SV2, r2[3]+b1[2]*SV2};
        fv4 o3 = {r3[0]+b2[2]*SV2, r3[1]+b3[2]*SV2, r3[2]+b4[2]*SV2, r3[3]+b0[3]*SV2};
        fv4 o4 = {r4[0]+b1[3]*SV2, r4[1]+b2[3]*SV2, r4[2]+b3[3]*SV2, r4[3]+b4[3]*SV2};
        NTS(yrow + base, o0); NTS(yrow + base + 4, o1); NTS(yrow + base + 8, o2);
        NTS(yrow + base + 12, o3); NTS(yrow + base + 16, o4);
    }
}

static float compute_cssp() {
    const int N = 200001;
    const double dz = 20.0 / 200000.0;
    double sum = 0.0;
    for (int i = 0; i < N; i++) {
        double z = -10.0 + dz * i;
        double f = (z > 0 ? z : 0.0) + log1p(exp(-fabs(z))) - 0.69314718055994530942;
        double phi = exp(-0.5 * z * z) * 0.39894228040143267794;
        double y = f * f * phi;
        sum += (i == 0 || i == N - 1) ? 0.5 * y : y;
    }
    return (float)(1.0 / sqrt(sum * dz));
}

extern "C" void kernel_launch(void* const* d_in, const int* in_sizes, int n_in,
                              void* d_out, int out_size, void* d_ws, size_t ws_size,
                              hipStream_t stream) {
    const float* x    = (const float*)d_in[0];
    const float* w1s  = (const float*)d_in[1];
    const float* w1v1 = (const float*)d_in[2];
    const float* w1v2 = (const float*)d_in[3];
    const float* w2s  = (const float*)d_in[4];
    const float* w2v1 = (const float*)d_in[5];
    const float* w2v2 = (const float*)d_in[6];
    float* out = (float*)d_out;

    static const float c_ssp = compute_cssp();

    int rows = in_sizes[0] / XP;
    int blocks = rows / 64;

    pack_weights<<<108, 256, 0, stream>>>(w1s, w1v1, w1v2, w2s, w2v1, w2v2);
    fused_kernel<<<blocks, 256, 0, stream>>>(x, out, c_ssp);
}